// Round 17
// baseline (459.061 us; speedup 1.0000x reference)
//
#include <hip/hip_runtime.h>
#include <hip/hip_bf16.h>

typedef __attribute__((ext_vector_type(8))) __bf16 bf16x8;
typedef __attribute__((ext_vector_type(4))) float f32x4;
typedef __attribute__((ext_vector_type(4))) unsigned short us4;

__device__ __forceinline__ unsigned short f2bf(float f){
  union { float f; unsigned int u; } a; a.f = f;
  unsigned int r = 0x7fffu + ((a.u >> 16) & 1u);
  return (unsigned short)((a.u + r) >> 16);
}

__device__ __forceinline__ unsigned int cvt_pk_bf16(float lo, float hi){
  unsigned int d;
  asm("v_cvt_pk_bf16_f32 %0, %1, %2" : "=v"(d) : "v"(lo), "v"(hi));
  return d;
}

__device__ __forceinline__ float exp2_hw(float x){
  float d;
  asm("v_exp_f32 %0, %1" : "=v"(d) : "v"(x));
  return d;
}

__device__ __forceinline__ float rcp_hw(float x){
  float d;
  asm("v_rcp_f32 %0, %1" : "=v"(d) : "v"(x));
  return d;
}

__device__ __forceinline__ void gload_lds16(const unsigned short* g, void* l){
  __builtin_amdgcn_global_load_lds(
      (const __attribute__((address_space(1))) void*)g,
      (__attribute__((address_space(3))) void*)l, 16, 0, 0);
}

// ---------------- batched cast fp32 -> bf16: all 11 tensors in ONE launch ----------------
struct CastJobs {
  const float* src[11];
  unsigned short* dst[11];
  int blkStart[12];
};

__global__ __launch_bounds__(256) void cast_all_kernel(CastJobs jobs){
  int bid = blockIdx.x;
  int j = 0;
  #pragma unroll
  for (int i = 0; i < 11; i++) j += (bid >= jobs.blkStart[i + 1]) ? 1 : 0;
  int i4 = (bid - jobs.blkStart[j]) * 256 + threadIdx.x;
  float4 v = ((const float4*)jobs.src[j])[i4];
  us4 o; o.x = f2bf(v.x); o.y = f2bf(v.y); o.z = f2bf(v.z); o.w = f2bf(v.w);
  ((us4*)jobs.dst[j])[i4] = o;
}

// ---------------- modulation: y = silu(emb) @ w.T (3 matrices of 3072x1024) ----------------
__global__ __launch_bounds__(256) void modulation_kernel(const float* __restrict__ emb,
    const float* __restrict__ w0, const float* __restrict__ w1, const float* __restrict__ w2,
    float* __restrict__ out){
  int gw = blockIdx.x * 4 + (threadIdx.x >> 6);
  int lane = threadIdx.x & 63;
  int mat = gw / 3072, row = gw % 3072;
  const float* w = (mat == 0) ? w0 : (mat == 1 ? w1 : w2);
  float acc = 0.f;
  for (int i = lane; i < 1024; i += 64){
    float e = emb[i];
    float s = e / (1.f + expf(-e));
    acc += s * w[row * 1024 + i];
  }
  #pragma unroll
  for (int m = 32; m >= 1; m >>= 1) acc += __shfl_xor(acc, m, 64);
  if (lane == 0) out[mat * 3072 + row] = acc;
}

// ---------------- layernorm * (1+scale) + shift -> bf16 ----------------
__global__ __launch_bounds__(256) void ln_mod_kernel(const float* __restrict__ x,
    const float* __restrict__ mod, unsigned short* __restrict__ h){
  int row = blockIdx.x, t = threadIdx.x;
  const float* xr = x + (size_t)row * 1024;
  float4 v = ((const float4*)xr)[t];
  float s = v.x + v.y + v.z + v.w;
  #pragma unroll
  for (int m = 32; m >= 1; m >>= 1) s += __shfl_xor(s, m, 64);
  __shared__ float red[4], red2[4];
  int wid = t >> 6, lane = t & 63;
  if (lane == 0) red[wid] = s;
  __syncthreads();
  float mean = (red[0] + red[1] + red[2] + red[3]) * (1.f / 1024.f);
  float dx = v.x - mean, dy = v.y - mean, dz = v.z - mean, dw = v.w - mean;
  float s2 = dx*dx + dy*dy + dz*dz + dw*dw;
  #pragma unroll
  for (int m = 32; m >= 1; m >>= 1) s2 += __shfl_xor(s2, m, 64);
  if (lane == 0) red2[wid] = s2;
  __syncthreads();
  float var = (red2[0] + red2[1] + red2[2] + red2[3]) * (1.f / 1024.f);
  float rs = rsqrtf(var + 1e-6f);
  int c = t * 4;
  us4 o;
  o.x = f2bf(dx * rs * (1.f + mod[1024 + c    ]) + mod[c    ]);
  o.y = f2bf(dy * rs * (1.f + mod[1024 + c + 1]) + mod[c + 1]);
  o.z = f2bf(dz * rs * (1.f + mod[1024 + c + 2]) + mod[c + 2]);
  o.w = f2bf(dw * rs * (1.f + mod[1024 + c + 3]) + mod[c + 3]);
  ((us4*)(h + (size_t)row * 1024))[t] = o;
}

// ---------------- merged rmsnorm(+rope) for q AND k in one launch ----------------
template<int ROPE>
__global__ __launch_bounds__(256) void qk_post2_kernel(
    const float* __restrict__ qin, const float* __restrict__ qnw,
    const float* __restrict__ kin, const float* __restrict__ knw,
    const float* __restrict__ rope,
    unsigned short* __restrict__ qout, unsigned short* __restrict__ kout,
    int Sq, int Sk, int qblocks){
  int bid = blockIdx.x;
  const float* in; const float* nw; unsigned short* out; int S;
  if (bid < qblocks){ in = qin; nw = qnw; out = qout; S = Sq; }
  else { in = kin; nw = knw; out = kout; S = Sk; bid -= qblocks; }
  int gw = bid * 4 + (threadIdx.x >> 6);
  int lane = threadIdx.x & 63;
  int s = gw >> 4, h = gw & 15;
  float v = in[(size_t)s * 1024 + h * 64 + lane];
  float ss = v * v;
  #pragma unroll
  for (int m = 32; m >= 1; m >>= 1) ss += __shfl_xor(ss, m, 64);
  float val = v * rsqrtf(ss * (1.f / 64.f) + 1e-6f) * nw[lane];
  if (ROPE){
    float partner = __shfl_xor(val, 32, 64);
    float cs = rope[s * 64 + (lane & 31)];
    float sn = rope[s * 64 + 32 + (lane & 31)];
    val = (lane < 32) ? (val * cs - partner * sn) : (val * cs + partner * sn);
  }
  out[((size_t)h * S + s) * 64 + lane] = f2bf(val);
}

// ---------------- GEMM 128x128 ----------------
// EPI: 0=fp32; 2=fast-gelu->bf16; 3=resid+gate; 4=split-store fp32; 5=split-store with
// V-columns (col>=vstart) written bf16 TRANSPOSED into outB[(h*64+d)*Sv + row] (fused vt).
template<int EPI>
__global__ __launch_bounds__(256) void gemm_bt_kernel(
    const unsigned short* __restrict__ A, const unsigned short* __restrict__ W,
    int M, int N, int K,
    float* __restrict__ outF, unsigned short* __restrict__ outB,
    const float* __restrict__ resid, const float* __restrict__ gate,
    int vstart, int Sv){
  __shared__ short As[128 * 64];
  __shared__ short Bs[128 * 64];
  const int t = threadIdx.x, wid = t >> 6, lane = t & 63;
  const int r = lane & 15, g = lane >> 4;
  const int brow = blockIdx.y * 128, bcol = blockIdx.x * 128;
  const int wr = wid >> 1, wc = wid & 1;
  f32x4 acc[4][4] = {};
  const int nkt = K >> 6;
  for (int kt = 0; kt < nkt; ++kt){
    const int k0 = kt << 6;
    #pragma unroll
    for (int i = 0; i < 4; i++){
      int chunk = wid * 4 + i;
      int rowi = chunk * 8 + (lane >> 3);
      int lce = ((lane & 7) * 8) ^ ((rowi & 7) << 3);
      gload_lds16(A + (size_t)(brow + rowi) * K + k0 + lce, (void*)(As + chunk * 512));
      gload_lds16(W + (size_t)(bcol + rowi) * K + k0 + lce, (void*)(Bs + chunk * 512));
    }
    __syncthreads();
    #pragma unroll
    for (int kk = 0; kk < 2; kk++){
      bf16x8 af[4], bfr[4];
      #pragma unroll
      for (int m = 0; m < 4; m++){
        int ar = wr * 64 + m * 16 + r;
        af[m] = *(const bf16x8*)(As + ar * 64 + ((kk * 32 + g * 8) ^ ((ar & 7) << 3)));
      }
      #pragma unroll
      for (int n = 0; n < 4; n++){
        int br = wc * 64 + n * 16 + r;
        bfr[n] = *(const bf16x8*)(Bs + br * 64 + ((kk * 32 + g * 8) ^ ((br & 7) << 3)));
      }
      #pragma unroll
      for (int m = 0; m < 4; m++)
        #pragma unroll
        for (int n = 0; n < 4; n++)
          acc[m][n] = __builtin_amdgcn_mfma_f32_16x16x32_bf16(af[m], bfr[n], acc[m][n], 0, 0, 0);
    }
    __syncthreads();
  }
  #pragma unroll
  for (int m = 0; m < 4; m++){
    #pragma unroll
    for (int n = 0; n < 4; n++){
      int col = bcol + wc * 64 + n * 16 + r;
      #pragma unroll
      for (int j = 0; j < 4; j++){
        int rowj = brow + wr * 64 + m * 16 + g * 4 + j;
        float v = acc[m][n][j];
        if (EPI == 0){
          outF[(size_t)rowj * N + col] = v;
        } else if (EPI == 2){
          float u = v * fmaf(v * v, 0.044715f, 1.0f);
          float e = exp2_hw(u * 2.3022077f);
          float gl = v * (1.f - rcp_hw(e + 1.f));
          outB[(size_t)rowj * N + col] = f2bf(gl);
        } else if (EPI == 4){
          outF[(size_t)(col >> 10) * 4194304 + (size_t)rowj * 1024 + (col & 1023)] = v;
        } else if (EPI == 5){
          if (col < vstart){
            outF[(size_t)(col >> 10) * 4194304 + (size_t)rowj * 1024 + (col & 1023)] = v;
          } else {
            int vc = col - vstart;
            outB[(size_t)vc * Sv + rowj] = f2bf(v);
          }
        } else {
          outF[(size_t)rowj * N + col] = resid[(size_t)rowj * N + col] + gate[col] * v;
        }
      }
    }
  }
}

// ---------------- GEMM 128x128 split-K=2 ----------------
__global__ __launch_bounds__(256) void gemm_bt128_sk_kernel(
    const unsigned short* __restrict__ A, const unsigned short* __restrict__ W,
    int M, int N, int K, float* __restrict__ outP){
  __shared__ short As[128 * 64];
  __shared__ short Bs[128 * 64];
  const int t = threadIdx.x, wid = t >> 6, lane = t & 63;
  const int r = lane & 15, g = lane >> 4;
  const int brow = blockIdx.y * 128, bcol = blockIdx.x * 128;
  const int wr = wid >> 1, wc = wid & 1;
  const int zk = blockIdx.z;
  const int koff = zk * (K >> 1);
  float* out = outP + (size_t)zk * 4194304;
  f32x4 acc[4][4] = {};
  const int nkt = K >> 7;
  for (int kt = 0; kt < nkt; ++kt){
    const int k0 = koff + (kt << 6);
    #pragma unroll
    for (int i = 0; i < 4; i++){
      int chunk = wid * 4 + i;
      int rowi = chunk * 8 + (lane >> 3);
      int lce = ((lane & 7) * 8) ^ ((rowi & 7) << 3);
      gload_lds16(A + (size_t)(brow + rowi) * K + k0 + lce, (void*)(As + chunk * 512));
      gload_lds16(W + (size_t)(bcol + rowi) * K + k0 + lce, (void*)(Bs + chunk * 512));
    }
    __syncthreads();
    #pragma unroll
    for (int kk = 0; kk < 2; kk++){
      bf16x8 af[4], bfr[4];
      #pragma unroll
      for (int m = 0; m < 4; m++){
        int ar = wr * 64 + m * 16 + r;
        af[m] = *(const bf16x8*)(As + ar * 64 + ((kk * 32 + g * 8) ^ ((ar & 7) << 3)));
      }
      #pragma unroll
      for (int n = 0; n < 4; n++){
        int br = wc * 64 + n * 16 + r;
        bfr[n] = *(const bf16x8*)(Bs + br * 64 + ((kk * 32 + g * 8) ^ ((br & 7) << 3)));
      }
      #pragma unroll
      for (int m = 0; m < 4; m++)
        #pragma unroll
        for (int n = 0; n < 4; n++)
          acc[m][n] = __builtin_amdgcn_mfma_f32_16x16x32_bf16(af[m], bfr[n], acc[m][n], 0, 0, 0);
    }
    __syncthreads();
  }
  #pragma unroll
  for (int m = 0; m < 4; m++){
    #pragma unroll
    for (int n = 0; n < 4; n++){
      int col = bcol + wc * 64 + n * 16 + r;
      #pragma unroll
      for (int j = 0; j < 4; j++){
        int rowj = brow + wr * 64 + m * 16 + g * 4 + j;
        out[(size_t)rowj * N + col] = acc[m][n][j];
      }
    }
  }
}

// ---------------- GEMM 64x128 ----------------
template<int EPI>
__global__ __launch_bounds__(256) void gemm_bt64_kernel(
    const unsigned short* __restrict__ A, const unsigned short* __restrict__ W,
    int M, int N, int K,
    float* __restrict__ outF, unsigned short* __restrict__ outB,
    const float* __restrict__ resid, const float* __restrict__ gate,
    int vstart, int Sv){
  __shared__ short As[64 * 64];
  __shared__ short Bs[128 * 64];
  const int t = threadIdx.x, wid = t >> 6, lane = t & 63;
  const int r = lane & 15, g = lane >> 4;
  const int brow = blockIdx.y * 64, bcol = blockIdx.x * 128;
  f32x4 acc[4][2] = {};
  const int nkt = K >> 6;
  const int sr = lane >> 3;
  const int lce = ((lane & 7) * 8) ^ ((sr & 7) << 3);
  for (int kt = 0; kt < nkt; ++kt){
    const int k0 = kt << 6;
    #pragma unroll
    for (int i = 0; i < 2; i++){
      int chunk = wid * 2 + i;
      gload_lds16(A + (size_t)(brow + chunk * 8 + sr) * K + k0 + lce, (void*)(As + chunk * 512));
    }
    #pragma unroll
    for (int i = 0; i < 4; i++){
      int chunk = wid * 4 + i;
      gload_lds16(W + (size_t)(bcol + chunk * 8 + sr) * K + k0 + lce, (void*)(Bs + chunk * 512));
    }
    __syncthreads();
    #pragma unroll
    for (int kk = 0; kk < 2; kk++){
      bf16x8 af[4], bfr[2];
      #pragma unroll
      for (int m = 0; m < 4; m++){
        int ar = m * 16 + r;
        af[m] = *(const bf16x8*)(As + ar * 64 + ((kk * 32 + g * 8) ^ ((ar & 7) << 3)));
      }
      #pragma unroll
      for (int n = 0; n < 2; n++){
        int br = wid * 32 + n * 16 + r;
        bfr[n] = *(const bf16x8*)(Bs + br * 64 + ((kk * 32 + g * 8) ^ ((br & 7) << 3)));
      }
      #pragma unroll
      for (int m = 0; m < 4; m++)
        #pragma unroll
        for (int n = 0; n < 2; n++)
          acc[m][n] = __builtin_amdgcn_mfma_f32_16x16x32_bf16(af[m], bfr[n], acc[m][n], 0, 0, 0);
    }
    __syncthreads();
  }
  #pragma unroll
  for (int m = 0; m < 4; m++){
    #pragma unroll
    for (int n = 0; n < 2; n++){
      int col = bcol + wid * 32 + n * 16 + r;
      #pragma unroll
      for (int j = 0; j < 4; j++){
        int rowj = brow + m * 16 + g * 4 + j;
        float v = acc[m][n][j];
        if (EPI == 0){
          outF[(size_t)rowj * N + col] = v;
        } else if (EPI == 4){
          outF[(size_t)(col >> 10) * 4194304 + (size_t)rowj * 1024 + (col & 1023)] = v;
        } else if (EPI == 5){
          if (col < vstart){
            outF[(size_t)(col >> 10) * 4194304 + (size_t)rowj * 1024 + (col & 1023)] = v;
          } else {
            int vc = col - vstart;
            outB[(size_t)vc * Sv + rowj] = f2bf(v);
          }
        } else {
          outF[(size_t)rowj * N + col] = resid[(size_t)rowj * N + col] + gate[col] * v;
        }
      }
    }
  }
}

// ---------------- split-K reduce: xio += gate[col] * (p0 + p1) ----------------
__global__ __launch_bounds__(256) void reduce_gg_kernel(const float* __restrict__ p0,
    const float* __restrict__ p1, const float* __restrict__ gate, float* __restrict__ xio){
  int i4 = blockIdx.x * 256 + threadIdx.x;
  float4 a = ((const float4*)p0)[i4];
  float4 b = ((const float4*)p1)[i4];
  float4 rr = ((const float4*)xio)[i4];
  int col = (i4 * 4) & 1023;
  float4 gv = *(const float4*)&gate[col];
  float4 o;
  o.x = rr.x + gv.x * (a.x + b.x);
  o.y = rr.y + gv.y * (a.y + b.y);
  o.z = rr.z + gv.z * (a.z + b.z);
  o.w = rr.w + gv.w * (a.w + b.w);
  ((float4*)xio)[i4] = o;
}

// ---------------- flash attention: triple-buffered K/V, counted vmcnt, QT q-tiles/wave ----------------
// QT=4: 64 q-rows/wave, 256/block, grid 256 = 1 blk/CU; K/V ds_reads shared across 4 q-tiles
// (24 reads per 64 MFMA vs 20 per 32). LDS 80KB. QT=2: proven R12 geometry (cross-attn).
template<int QT>
__global__ __launch_bounds__(256) void attn_kernel(
    const unsigned short* __restrict__ Qb, const unsigned short* __restrict__ Kb,
    const unsigned short* __restrict__ Vtg, unsigned short* __restrict__ Out,
    int Sq, int Skv){
  __shared__ short Ks[3][4096];
  __shared__ short Vs[3][4096];
  __shared__ unsigned short Ps[4][QT * 1024];
  const int t = threadIdx.x, wid = t >> 6, lane = t & 63;
  const int r = lane & 15, g = lane >> 4;
  const int bid = blockIdx.x;
  const int slot = bid >> 3;
  const int qbn = 64 / QT;                       // q-blocks per head
  const int h = (bid & 7) * 2 + (slot / qbn);
  const int qblk = slot % qbn;
  const int qbase = qblk * (QT * 64) + wid * (QT * 16);
  const float SC = 0.18033688f;
  const float MS = 12.0f;

  const int srow0 = wid * 16 + (lane >> 3);
  const int scol  = ((lane & 7) * 8) ^ (((lane >> 3) & 7) << 3);
  const unsigned short* kSrc0 = Kb + ((size_t)h * Skv + srow0) * 64 + scol;
  const unsigned short* kSrc1 = kSrc0 + 8 * 64;
  const unsigned short* vSrc0 = Vtg + ((size_t)h * 64 + srow0) * Skv + scol;
  const unsigned short* vSrc1 = vSrc0 + (size_t)8 * Skv;

  bf16x8 qf[QT][2];
  #pragma unroll
  for (int qt = 0; qt < QT; qt++){
    const unsigned short* qp = Qb + ((size_t)h * Sq + qbase + qt * 16 + r) * 64 + g * 8;
    qf[qt][0] = *(const bf16x8*)qp;
    qf[qt][1] = *(const bf16x8*)(qp + 32);
  }
  f32x4 o[QT][4] = {};
  f32x4 lacc[QT] = {};

  const int nkv = Skv >> 6;

  gload_lds16(kSrc0, (void*)&Ks[0][(wid * 2 + 0) * 512]);
  gload_lds16(kSrc1, (void*)&Ks[0][(wid * 2 + 1) * 512]);
  gload_lds16(vSrc0, (void*)&Vs[0][(wid * 2 + 0) * 512]);
  gload_lds16(vSrc1, (void*)&Vs[0][(wid * 2 + 1) * 512]);
  gload_lds16(kSrc0 + 4096, (void*)&Ks[1][(wid * 2 + 0) * 512]);
  gload_lds16(kSrc1 + 4096, (void*)&Ks[1][(wid * 2 + 1) * 512]);
  gload_lds16(vSrc0 + 64, (void*)&Vs[1][(wid * 2 + 0) * 512]);
  gload_lds16(vSrc1 + 64, (void*)&Vs[1][(wid * 2 + 1) * 512]);
  asm volatile("s_waitcnt vmcnt(4)" ::: "memory");
  __builtin_amdgcn_s_barrier();

  int cur = 0, stg = 2;
  for (int it = 0; it < nkv; ++it){
    if (it + 2 < nkv){
      size_t ko = (size_t)(it + 2) << 12;
      size_t vo = (size_t)(it + 2) << 6;
      gload_lds16(kSrc0 + ko, (void*)&Ks[stg][(wid * 2 + 0) * 512]);
      gload_lds16(kSrc1 + ko, (void*)&Ks[stg][(wid * 2 + 1) * 512]);
      gload_lds16(vSrc0 + vo, (void*)&Vs[stg][(wid * 2 + 0) * 512]);
      gload_lds16(vSrc1 + vo, (void*)&Vs[stg][(wid * 2 + 1) * 512]);
    }
    const short* kb = &Ks[cur][0];
    const short* vb = &Vs[cur][0];

    // ---- S^T = K·Q^T: K frags read once, shared across all QT q-tiles ----
    f32x4 pT[QT][4];
    __builtin_amdgcn_s_setprio(1);
    #pragma unroll
    for (int kt = 0; kt < 4; kt++){
      int kr = kt * 16 + r;
      bf16x8 k0 = *(const bf16x8*)(kb + kr * 64 + ((g * 8) ^ ((kr & 7) << 3)));
      bf16x8 k1 = *(const bf16x8*)(kb + kr * 64 + ((32 + g * 8) ^ ((kr & 7) << 3)));
      #pragma unroll
      for (int qt = 0; qt < QT; qt++){
        f32x4 a = {};
        a = __builtin_amdgcn_mfma_f32_16x16x32_bf16(k0, qf[qt][0], a, 0, 0, 0);
        a = __builtin_amdgcn_mfma_f32_16x16x32_bf16(k1, qf[qt][1], a, 0, 0, 0);
        pT[qt][kt] = a;
      }
    }
    __builtin_amdgcn_s_setprio(0);

    // ---- fixed-max softmax (per-lane VALU only) ----
    #pragma unroll
    for (int qt = 0; qt < QT; qt++){
      unsigned short* pw = &Ps[wid][(qt * 16 + r) * 64];
      int rx = (r & 7) << 3;
      #pragma unroll
      for (int kt = 0; kt < 4; kt++){
        f32x4 pe;
        #pragma unroll
        for (int e = 0; e < 4; e++) pe[e] = exp2_hw(fmaf(pT[qt][kt][e], SC, -MS));
        lacc[qt] += pe;
        unsigned int w0 = cvt_pk_bf16(pe[0], pe[1]);
        unsigned int w1 = cvt_pk_bf16(pe[2], pe[3]);
        *(uint2*)(pw + ((kt * 16 + g * 4) ^ rx)) = make_uint2(w0, w1);
      }
    }

    // ---- PV: P frags hoisted; dj outer, qt inner -> each V frag read ONCE for QT tiles ----
    __builtin_amdgcn_s_setprio(1);
    {
      bf16x8 pf[QT][2];
      int rx = (r & 7) << 3;
      #pragma unroll
      for (int qt = 0; qt < QT; qt++){
        const unsigned short* pw = &Ps[wid][(qt * 16 + r) * 64];
        pf[qt][0] = *(const bf16x8*)(pw + ((g * 8) ^ rx));
        pf[qt][1] = *(const bf16x8*)(pw + ((32 + g * 8) ^ rx));
      }
      #pragma unroll
      for (int dj = 0; dj < 4; dj++){
        int vrow = dj * 16 + r;
        bf16x8 v0 = *(const bf16x8*)(vb + vrow * 64 + ((g * 8) ^ ((vrow & 7) << 3)));
        bf16x8 v1 = *(const bf16x8*)(vb + vrow * 64 + ((32 + g * 8) ^ ((vrow & 7) << 3)));
        #pragma unroll
        for (int qt = 0; qt < QT; qt++){
          o[qt][dj] = __builtin_amdgcn_mfma_f32_16x16x32_bf16(pf[qt][0], v0, o[qt][dj], 0, 0, 0);
          o[qt][dj] = __builtin_amdgcn_mfma_f32_16x16x32_bf16(pf[qt][1], v1, o[qt][dj], 0, 0, 0);
        }
      }
    }
    __builtin_amdgcn_s_setprio(0);

    if (it + 1 < nkv){
      if (it + 2 < nkv) asm volatile("s_waitcnt vmcnt(4)" ::: "memory");
      else              asm volatile("s_waitcnt vmcnt(0)" ::: "memory");
      __builtin_amdgcn_s_barrier();
    }
    cur = (cur == 2) ? 0 : cur + 1;
    stg = (stg == 2) ? 0 : stg + 1;
  }

  #pragma unroll
  for (int qt = 0; qt < QT; qt++){
    float s = (lacc[qt][0] + lacc[qt][1]) + (lacc[qt][2] + lacc[qt][3]);
    s += __shfl_xor(s, 16, 64);
    s += __shfl_xor(s, 32, 64);
    float inv = 1.f / s;
    int sb = lane & 48;
    #pragma unroll
    for (int j = 0; j < 4; j++){
      float aj = __shfl(inv, sb + g * 4 + j, 64);
      int qrow = qbase + qt * 16 + g * 4 + j;
      #pragma unroll
      for (int dj = 0; dj < 4; dj++)
        Out[(size_t)qrow * 1024 + h * 64 + dj * 16 + r] = f2bf(o[qt][dj][j] * aj);
    }
  }
}

extern "C" void kernel_launch(void* const* d_in, const int* in_sizes, int n_in,
                              void* d_out, int out_size, void* d_ws, size_t ws_size,
                              hipStream_t stream){
  (void)n_in; (void)out_size;
  const float* x   = (const float*)d_in[0];
  const float* emb = (const float*)d_in[1];
  const float* ctx = (const float*)d_in[2];
  int wb = 3, ri = 20;
  if (in_sizes[3] == 4096 * 64) { ri = 3; wb = 4; }
  const float* rope  = (const float*)d_in[ri];
  const float* sa_wq = (const float*)d_in[wb + 0];
  const float* sa_wk = (const float*)d_in[wb + 1];
  const float* sa_wv = (const float*)d_in[wb + 2];
  const float* sa_wo = (const float*)d_in[wb + 3];
  const float* sa_qn = (const float*)d_in[wb + 4];
  const float* sa_kn = (const float*)d_in[wb + 5];
  const float* ca_wq = (const float*)d_in[wb + 6];
  const float* ca_wk = (const float*)d_in[wb + 7];
  const float* ca_wv = (const float*)d_in[wb + 8];
  const float* ca_wo = (const float*)d_in[wb + 9];
  const float* ca_qn = (const float*)d_in[wb + 10];
  const float* ca_kn = (const float*)d_in[wb + 11];
  const float* w1    = (const float*)d_in[wb + 12];
  const float* w2    = (const float*)d_in[wb + 13];
  const float* msa   = (const float*)d_in[wb + 14];
  const float* mca   = (const float*)d_in[wb + 15];
  const float* mmlp  = (const float*)d_in[wb + 16];

  char* ws = (char*)d_ws;
  const size_t MB = 1u << 20;
  if (ws_size < 114 * MB) return;
  unsigned short* wq_sa = (unsigned short*)(ws + 0 * MB);
  unsigned short* wk_sa = (unsigned short*)(ws + 2 * MB);
  unsigned short* wv_sa = (unsigned short*)(ws + 4 * MB);
  unsigned short* wo_sa = (unsigned short*)(ws + 6 * MB);
  unsigned short* wq_ca = (unsigned short*)(ws + 8 * MB);
  unsigned short* wk_ca = (unsigned short*)(ws + 10 * MB);
  unsigned short* wv_ca = (unsigned short*)(ws + 12 * MB);
  unsigned short* wo_ca = (unsigned short*)(ws + 14 * MB);
  unsigned short* w1bf  = (unsigned short*)(ws + 16 * MB);
  unsigned short* w2bf  = (unsigned short*)(ws + 24 * MB);
  unsigned short* ctxbf = (unsigned short*)(ws + 32 * MB);
  float*          modv  = (float*)(ws + 33 * MB);
  unsigned short* hbf   = (unsigned short*)(ws + 34 * MB);
  unsigned short* qbf   = (unsigned short*)(ws + 42 * MB);
  unsigned short* kbf   = (unsigned short*)(ws + 50 * MB);
  unsigned short* aobf  = (unsigned short*)(ws + 58 * MB);
  float*          qf32  = (float*)(ws + 66 * MB);
  float*          kca32 = (float*)(ws + 82 * MB);
  unsigned short* vtb   = (unsigned short*)(ws + 98 * MB);
  unsigned short* midbf = (unsigned short*)(ws + 66 * MB);
  float*          mp0   = (float*)(ws + 34 * MB);
  float*          mp1   = (float*)(ws + 50 * MB);
  float* xcur = (float*)d_out;

  CastJobs cj;
  const float* srcs[11] = {sa_wq, sa_wk, sa_wv, sa_wo, ca_wq, ca_wk, ca_wv, ca_wo, w1, w2, ctx};
  unsigned short* dsts[11] = {wq_sa, wk_sa, wv_sa, wo_sa, wq_ca, wk_ca, wv_ca, wo_ca, w1bf, w2bf, ctxbf};
  int n4s[11] = {262144, 262144, 262144, 262144, 262144, 262144, 262144, 262144, 1048576, 1048576, 131072};
  int cum = 0;
  for (int i = 0; i < 11; i++){
    cj.src[i] = srcs[i]; cj.dst[i] = dsts[i];
    cj.blkStart[i] = cum; cum += n4s[i] / 256;
  }
  cj.blkStart[11] = cum;
  cast_all_kernel<<<cum, 256, 0, stream>>>(cj);
  modulation_kernel<<<2304, 256, 0, stream>>>(emb, msa, mca, mmlp, modv);

  // ---- self attention (QT=4: 256 q-rows/block, grid 256) ----
  ln_mod_kernel<<<4096, 256, 0, stream>>>(x, modv + 0 * 3072, hbf);
  gemm_bt_kernel<5><<<dim3(24, 32), 256, 0, stream>>>(hbf, wq_sa, 4096, 3072, 1024, qf32, vtb, nullptr, nullptr, 2048, 4096);
  qk_post2_kernel<1><<<32768, 256, 0, stream>>>(qf32, sa_qn, qf32 + 4194304, sa_kn, rope, qbf, kbf, 4096, 4096, 16384);
  attn_kernel<4><<<256, 256, 0, stream>>>(qbf, kbf, vtb, aobf, 4096, 4096);
  gemm_bt64_kernel<3><<<dim3(8, 64), 256, 0, stream>>>(aobf, wo_sa, 4096, 1024, 1024, xcur, nullptr, x, modv + 0 * 3072 + 2048, 0, 0);

  // ---- cross attention (QT=2: proven geometry) ----
  ln_mod_kernel<<<4096, 256, 0, stream>>>(xcur, modv + 1 * 3072, hbf);
  gemm_bt64_kernel<0><<<dim3(8, 64), 256, 0, stream>>>(hbf, wq_ca, 4096, 1024, 1024, qf32, nullptr, nullptr, nullptr, 0, 0);
  gemm_bt64_kernel<5><<<dim3(16, 8), 256, 0, stream>>>(ctxbf, wk_ca, 512, 2048, 1024, kca32, vtb, nullptr, nullptr, 1024, 512);
  qk_post2_kernel<0><<<18432, 256, 0, stream>>>(qf32, ca_qn, kca32, ca_kn, nullptr, qbf, kbf, 4096, 512, 16384);
  attn_kernel<2><<<512, 256, 0, stream>>>(qbf, kbf, vtb, aobf, 4096, 512);
  gemm_bt64_kernel<3><<<dim3(8, 64), 256, 0, stream>>>(aobf, wo_ca, 4096, 1024, 1024, xcur, nullptr, xcur, modv + 1 * 3072 + 2048, 0, 0);

  // ---- mlp ----
  ln_mod_kernel<<<4096, 256, 0, stream>>>(xcur, modv + 2 * 3072, hbf);
  gemm_bt_kernel<2><<<dim3(32, 32), 256, 0, stream>>>(hbf, w1bf, 4096, 4096, 1024, nullptr, midbf, nullptr, nullptr, 0, 0);
  gemm_bt128_sk_kernel<<<dim3(8, 32, 2), 256, 0, stream>>>(midbf, w2bf, 4096, 1024, 4096, mp0);
  reduce_gg_kernel<<<4096, 256, 0, stream>>>(mp0, mp1, modv + 2 * 3072 + 2048, xcur);
}

// Round 18
// 427.388 us; speedup vs baseline: 1.0741x; 1.0741x over previous
//
#include <hip/hip_runtime.h>
#include <hip/hip_bf16.h>

typedef __attribute__((ext_vector_type(8))) __bf16 bf16x8;
typedef __attribute__((ext_vector_type(4))) float f32x4;
typedef __attribute__((ext_vector_type(4))) unsigned short us4;

__device__ __forceinline__ unsigned short f2bf(float f){
  union { float f; unsigned int u; } a; a.f = f;
  unsigned int r = 0x7fffu + ((a.u >> 16) & 1u);
  return (unsigned short)((a.u + r) >> 16);
}

__device__ __forceinline__ unsigned int cvt_pk_bf16(float lo, float hi){
  unsigned int d;
  asm("v_cvt_pk_bf16_f32 %0, %1, %2" : "=v"(d) : "v"(lo), "v"(hi));
  return d;
}

__device__ __forceinline__ float exp2_hw(float x){
  float d;
  asm("v_exp_f32 %0, %1" : "=v"(d) : "v"(x));
  return d;
}

__device__ __forceinline__ float rcp_hw(float x){
  float d;
  asm("v_rcp_f32 %0, %1" : "=v"(d) : "v"(x));
  return d;
}

__device__ __forceinline__ void gload_lds16(const unsigned short* g, void* l){
  __builtin_amdgcn_global_load_lds(
      (const __attribute__((address_space(1))) void*)g,
      (__attribute__((address_space(3))) void*)l, 16, 0, 0);
}

// ---------------- batched cast fp32 -> bf16: all 11 tensors in ONE launch ----------------
struct CastJobs {
  const float* src[11];
  unsigned short* dst[11];
  int blkStart[12];
};

__global__ __launch_bounds__(256) void cast_all_kernel(CastJobs jobs){
  int bid = blockIdx.x;
  int j = 0;
  #pragma unroll
  for (int i = 0; i < 11; i++) j += (bid >= jobs.blkStart[i + 1]) ? 1 : 0;
  int i4 = (bid - jobs.blkStart[j]) * 256 + threadIdx.x;
  float4 v = ((const float4*)jobs.src[j])[i4];
  us4 o; o.x = f2bf(v.x); o.y = f2bf(v.y); o.z = f2bf(v.z); o.w = f2bf(v.w);
  ((us4*)jobs.dst[j])[i4] = o;
}

// ---------------- modulation: y = silu(emb) @ w.T (3 matrices of 3072x1024) ----------------
__global__ __launch_bounds__(256) void modulation_kernel(const float* __restrict__ emb,
    const float* __restrict__ w0, const float* __restrict__ w1, const float* __restrict__ w2,
    float* __restrict__ out){
  int gw = blockIdx.x * 4 + (threadIdx.x >> 6);
  int lane = threadIdx.x & 63;
  int mat = gw / 3072, row = gw % 3072;
  const float* w = (mat == 0) ? w0 : (mat == 1 ? w1 : w2);
  float acc = 0.f;
  for (int i = lane; i < 1024; i += 64){
    float e = emb[i];
    float s = e / (1.f + expf(-e));
    acc += s * w[row * 1024 + i];
  }
  #pragma unroll
  for (int m = 32; m >= 1; m >>= 1) acc += __shfl_xor(acc, m, 64);
  if (lane == 0) out[mat * 3072 + row] = acc;
}

// ---------------- layernorm * (1+scale) + shift -> bf16 ----------------
__global__ __launch_bounds__(256) void ln_mod_kernel(const float* __restrict__ x,
    const float* __restrict__ mod, unsigned short* __restrict__ h){
  int row = blockIdx.x, t = threadIdx.x;
  const float* xr = x + (size_t)row * 1024;
  float4 v = ((const float4*)xr)[t];
  float s = v.x + v.y + v.z + v.w;
  #pragma unroll
  for (int m = 32; m >= 1; m >>= 1) s += __shfl_xor(s, m, 64);
  __shared__ float red[4], red2[4];
  int wid = t >> 6, lane = t & 63;
  if (lane == 0) red[wid] = s;
  __syncthreads();
  float mean = (red[0] + red[1] + red[2] + red[3]) * (1.f / 1024.f);
  float dx = v.x - mean, dy = v.y - mean, dz = v.z - mean, dw = v.w - mean;
  float s2 = dx*dx + dy*dy + dz*dz + dw*dw;
  #pragma unroll
  for (int m = 32; m >= 1; m >>= 1) s2 += __shfl_xor(s2, m, 64);
  if (lane == 0) red2[wid] = s2;
  __syncthreads();
  float var = (red2[0] + red2[1] + red2[2] + red2[3]) * (1.f / 1024.f);
  float rs = rsqrtf(var + 1e-6f);
  int c = t * 4;
  us4 o;
  o.x = f2bf(dx * rs * (1.f + mod[1024 + c    ]) + mod[c    ]);
  o.y = f2bf(dy * rs * (1.f + mod[1024 + c + 1]) + mod[c + 1]);
  o.z = f2bf(dz * rs * (1.f + mod[1024 + c + 2]) + mod[c + 2]);
  o.w = f2bf(dw * rs * (1.f + mod[1024 + c + 3]) + mod[c + 3]);
  ((us4*)(h + (size_t)row * 1024))[t] = o;
}

// ---------------- merged rmsnorm(+rope) for q AND k in one launch ----------------
template<int ROPE>
__global__ __launch_bounds__(256) void qk_post2_kernel(
    const float* __restrict__ qin, const float* __restrict__ qnw,
    const float* __restrict__ kin, const float* __restrict__ knw,
    const float* __restrict__ rope,
    unsigned short* __restrict__ qout, unsigned short* __restrict__ kout,
    int Sq, int Sk, int qblocks){
  int bid = blockIdx.x;
  const float* in; const float* nw; unsigned short* out; int S;
  if (bid < qblocks){ in = qin; nw = qnw; out = qout; S = Sq; }
  else { in = kin; nw = knw; out = kout; S = Sk; bid -= qblocks; }
  int gw = bid * 4 + (threadIdx.x >> 6);
  int lane = threadIdx.x & 63;
  int s = gw >> 4, h = gw & 15;
  float v = in[(size_t)s * 1024 + h * 64 + lane];
  float ss = v * v;
  #pragma unroll
  for (int m = 32; m >= 1; m >>= 1) ss += __shfl_xor(ss, m, 64);
  float val = v * rsqrtf(ss * (1.f / 64.f) + 1e-6f) * nw[lane];
  if (ROPE){
    float partner = __shfl_xor(val, 32, 64);
    float cs = rope[s * 64 + (lane & 31)];
    float sn = rope[s * 64 + 32 + (lane & 31)];
    val = (lane < 32) ? (val * cs - partner * sn) : (val * cs + partner * sn);
  }
  out[((size_t)h * S + s) * 64 + lane] = f2bf(val);
}

// ---------------- GEMM 128x128 ----------------
// EPI: 0=fp32; 2=fast-gelu->bf16; 3=resid+gate; 4=split-store fp32; 5=split-store with
// V-columns (col>=vstart) written bf16 TRANSPOSED into outB[(h*64+d)*Sv + row] (fused vt).
template<int EPI>
__global__ __launch_bounds__(256) void gemm_bt_kernel(
    const unsigned short* __restrict__ A, const unsigned short* __restrict__ W,
    int M, int N, int K,
    float* __restrict__ outF, unsigned short* __restrict__ outB,
    const float* __restrict__ resid, const float* __restrict__ gate,
    int vstart, int Sv){
  __shared__ short As[128 * 64];
  __shared__ short Bs[128 * 64];
  const int t = threadIdx.x, wid = t >> 6, lane = t & 63;
  const int r = lane & 15, g = lane >> 4;
  const int brow = blockIdx.y * 128, bcol = blockIdx.x * 128;
  const int wr = wid >> 1, wc = wid & 1;
  f32x4 acc[4][4] = {};
  const int nkt = K >> 6;
  for (int kt = 0; kt < nkt; ++kt){
    const int k0 = kt << 6;
    #pragma unroll
    for (int i = 0; i < 4; i++){
      int chunk = wid * 4 + i;
      int rowi = chunk * 8 + (lane >> 3);
      int lce = ((lane & 7) * 8) ^ ((rowi & 7) << 3);
      gload_lds16(A + (size_t)(brow + rowi) * K + k0 + lce, (void*)(As + chunk * 512));
      gload_lds16(W + (size_t)(bcol + rowi) * K + k0 + lce, (void*)(Bs + chunk * 512));
    }
    __syncthreads();
    #pragma unroll
    for (int kk = 0; kk < 2; kk++){
      bf16x8 af[4], bfr[4];
      #pragma unroll
      for (int m = 0; m < 4; m++){
        int ar = wr * 64 + m * 16 + r;
        af[m] = *(const bf16x8*)(As + ar * 64 + ((kk * 32 + g * 8) ^ ((ar & 7) << 3)));
      }
      #pragma unroll
      for (int n = 0; n < 4; n++){
        int br = wc * 64 + n * 16 + r;
        bfr[n] = *(const bf16x8*)(Bs + br * 64 + ((kk * 32 + g * 8) ^ ((br & 7) << 3)));
      }
      #pragma unroll
      for (int m = 0; m < 4; m++)
        #pragma unroll
        for (int n = 0; n < 4; n++)
          acc[m][n] = __builtin_amdgcn_mfma_f32_16x16x32_bf16(af[m], bfr[n], acc[m][n], 0, 0, 0);
    }
    __syncthreads();
  }
  #pragma unroll
  for (int m = 0; m < 4; m++){
    #pragma unroll
    for (int n = 0; n < 4; n++){
      int col = bcol + wc * 64 + n * 16 + r;
      #pragma unroll
      for (int j = 0; j < 4; j++){
        int rowj = brow + wr * 64 + m * 16 + g * 4 + j;
        float v = acc[m][n][j];
        if (EPI == 0){
          outF[(size_t)rowj * N + col] = v;
        } else if (EPI == 2){
          float u = v * fmaf(v * v, 0.044715f, 1.0f);
          float e = exp2_hw(u * 2.3022077f);
          float gl = v * (1.f - rcp_hw(e + 1.f));
          outB[(size_t)rowj * N + col] = f2bf(gl);
        } else if (EPI == 4){
          outF[(size_t)(col >> 10) * 4194304 + (size_t)rowj * 1024 + (col & 1023)] = v;
        } else if (EPI == 5){
          if (col < vstart){
            outF[(size_t)(col >> 10) * 4194304 + (size_t)rowj * 1024 + (col & 1023)] = v;
          } else {
            int vc = col - vstart;
            outB[(size_t)vc * Sv + rowj] = f2bf(v);
          }
        } else {
          outF[(size_t)rowj * N + col] = resid[(size_t)rowj * N + col] + gate[col] * v;
        }
      }
    }
  }
}

// ---------------- GEMM 128x128 split-K=2 ----------------
__global__ __launch_bounds__(256) void gemm_bt128_sk_kernel(
    const unsigned short* __restrict__ A, const unsigned short* __restrict__ W,
    int M, int N, int K, float* __restrict__ outP){
  __shared__ short As[128 * 64];
  __shared__ short Bs[128 * 64];
  const int t = threadIdx.x, wid = t >> 6, lane = t & 63;
  const int r = lane & 15, g = lane >> 4;
  const int brow = blockIdx.y * 128, bcol = blockIdx.x * 128;
  const int wr = wid >> 1, wc = wid & 1;
  const int zk = blockIdx.z;
  const int koff = zk * (K >> 1);
  float* out = outP + (size_t)zk * 4194304;
  f32x4 acc[4][4] = {};
  const int nkt = K >> 7;
  for (int kt = 0; kt < nkt; ++kt){
    const int k0 = koff + (kt << 6);
    #pragma unroll
    for (int i = 0; i < 4; i++){
      int chunk = wid * 4 + i;
      int rowi = chunk * 8 + (lane >> 3);
      int lce = ((lane & 7) * 8) ^ ((rowi & 7) << 3);
      gload_lds16(A + (size_t)(brow + rowi) * K + k0 + lce, (void*)(As + chunk * 512));
      gload_lds16(W + (size_t)(bcol + rowi) * K + k0 + lce, (void*)(Bs + chunk * 512));
    }
    __syncthreads();
    #pragma unroll
    for (int kk = 0; kk < 2; kk++){
      bf16x8 af[4], bfr[4];
      #pragma unroll
      for (int m = 0; m < 4; m++){
        int ar = wr * 64 + m * 16 + r;
        af[m] = *(const bf16x8*)(As + ar * 64 + ((kk * 32 + g * 8) ^ ((ar & 7) << 3)));
      }
      #pragma unroll
      for (int n = 0; n < 4; n++){
        int br = wc * 64 + n * 16 + r;
        bfr[n] = *(const bf16x8*)(Bs + br * 64 + ((kk * 32 + g * 8) ^ ((br & 7) << 3)));
      }
      #pragma unroll
      for (int m = 0; m < 4; m++)
        #pragma unroll
        for (int n = 0; n < 4; n++)
          acc[m][n] = __builtin_amdgcn_mfma_f32_16x16x32_bf16(af[m], bfr[n], acc[m][n], 0, 0, 0);
    }
    __syncthreads();
  }
  #pragma unroll
  for (int m = 0; m < 4; m++){
    #pragma unroll
    for (int n = 0; n < 4; n++){
      int col = bcol + wc * 64 + n * 16 + r;
      #pragma unroll
      for (int j = 0; j < 4; j++){
        int rowj = brow + wr * 64 + m * 16 + g * 4 + j;
        out[(size_t)rowj * N + col] = acc[m][n][j];
      }
    }
  }
}

// ---------------- GEMM 64x128 ----------------
template<int EPI>
__global__ __launch_bounds__(256) void gemm_bt64_kernel(
    const unsigned short* __restrict__ A, const unsigned short* __restrict__ W,
    int M, int N, int K,
    float* __restrict__ outF, unsigned short* __restrict__ outB,
    const float* __restrict__ resid, const float* __restrict__ gate,
    int vstart, int Sv){
  __shared__ short As[64 * 64];
  __shared__ short Bs[128 * 64];
  const int t = threadIdx.x, wid = t >> 6, lane = t & 63;
  const int r = lane & 15, g = lane >> 4;
  const int brow = blockIdx.y * 64, bcol = blockIdx.x * 128;
  f32x4 acc[4][2] = {};
  const int nkt = K >> 6;
  const int sr = lane >> 3;
  const int lce = ((lane & 7) * 8) ^ ((sr & 7) << 3);
  for (int kt = 0; kt < nkt; ++kt){
    const int k0 = kt << 6;
    #pragma unroll
    for (int i = 0; i < 2; i++){
      int chunk = wid * 2 + i;
      gload_lds16(A + (size_t)(brow + chunk * 8 + sr) * K + k0 + lce, (void*)(As + chunk * 512));
    }
    #pragma unroll
    for (int i = 0; i < 4; i++){
      int chunk = wid * 4 + i;
      gload_lds16(W + (size_t)(bcol + chunk * 8 + sr) * K + k0 + lce, (void*)(Bs + chunk * 512));
    }
    __syncthreads();
    #pragma unroll
    for (int kk = 0; kk < 2; kk++){
      bf16x8 af[4], bfr[2];
      #pragma unroll
      for (int m = 0; m < 4; m++){
        int ar = m * 16 + r;
        af[m] = *(const bf16x8*)(As + ar * 64 + ((kk * 32 + g * 8) ^ ((ar & 7) << 3)));
      }
      #pragma unroll
      for (int n = 0; n < 2; n++){
        int br = wid * 32 + n * 16 + r;
        bfr[n] = *(const bf16x8*)(Bs + br * 64 + ((kk * 32 + g * 8) ^ ((br & 7) << 3)));
      }
      #pragma unroll
      for (int m = 0; m < 4; m++)
        #pragma unroll
        for (int n = 0; n < 2; n++)
          acc[m][n] = __builtin_amdgcn_mfma_f32_16x16x32_bf16(af[m], bfr[n], acc[m][n], 0, 0, 0);
    }
    __syncthreads();
  }
  #pragma unroll
  for (int m = 0; m < 4; m++){
    #pragma unroll
    for (int n = 0; n < 2; n++){
      int col = bcol + wid * 32 + n * 16 + r;
      #pragma unroll
      for (int j = 0; j < 4; j++){
        int rowj = brow + m * 16 + g * 4 + j;
        float v = acc[m][n][j];
        if (EPI == 0){
          outF[(size_t)rowj * N + col] = v;
        } else if (EPI == 4){
          outF[(size_t)(col >> 10) * 4194304 + (size_t)rowj * 1024 + (col & 1023)] = v;
        } else if (EPI == 5){
          if (col < vstart){
            outF[(size_t)(col >> 10) * 4194304 + (size_t)rowj * 1024 + (col & 1023)] = v;
          } else {
            int vc = col - vstart;
            outB[(size_t)vc * Sv + rowj] = f2bf(v);
          }
        } else {
          outF[(size_t)rowj * N + col] = resid[(size_t)rowj * N + col] + gate[col] * v;
        }
      }
    }
  }
}

// ---------------- split-K reduce: xio += gate[col] * (p0 + p1) ----------------
__global__ __launch_bounds__(256) void reduce_gg_kernel(const float* __restrict__ p0,
    const float* __restrict__ p1, const float* __restrict__ gate, float* __restrict__ xio){
  int i4 = blockIdx.x * 256 + threadIdx.x;
  float4 a = ((const float4*)p0)[i4];
  float4 b = ((const float4*)p1)[i4];
  float4 rr = ((const float4*)xio)[i4];
  int col = (i4 * 4) & 1023;
  float4 gv = *(const float4*)&gate[col];
  float4 o;
  o.x = rr.x + gv.x * (a.x + b.x);
  o.y = rr.y + gv.y * (a.y + b.y);
  o.z = rr.z + gv.z * (a.z + b.z);
  o.w = rr.w + gv.w * (a.w + b.w);
  ((float4*)xio)[i4] = o;
}

// ---------------- flash attention: triple-buffered K/V, counted vmcnt, hoisted-P PV ----------------
// R17 lesson: 32 q-rows/wave (QT=2, 2 blk/CU) is the measured optimum of the q-tile axis
// (16 rows worse [R9], 64 rows worse [R17]).
__global__ __launch_bounds__(256) void attn_kernel(
    const unsigned short* __restrict__ Qb, const unsigned short* __restrict__ Kb,
    const unsigned short* __restrict__ Vtg, unsigned short* __restrict__ Out,
    int Sq, int Skv){
  __shared__ short Ks[3][4096];
  __shared__ short Vs[3][4096];
  __shared__ unsigned short Ps[4][2048];
  const int t = threadIdx.x, wid = t >> 6, lane = t & 63;
  const int r = lane & 15, g = lane >> 4;
  const int bid = blockIdx.x;
  const int slot = bid >> 3;
  const int h = (bid & 7) * 2 + (slot >> 5);
  const int qblk = slot & 31;
  const int qbase = qblk * 128 + wid * 32;
  const float SC = 0.18033688f;
  const float MS = 12.0f;

  const int srow0 = wid * 16 + (lane >> 3);
  const int scol  = ((lane & 7) * 8) ^ (((lane >> 3) & 7) << 3);
  const unsigned short* kSrc0 = Kb + ((size_t)h * Skv + srow0) * 64 + scol;
  const unsigned short* kSrc1 = kSrc0 + 8 * 64;
  const unsigned short* vSrc0 = Vtg + ((size_t)h * 64 + srow0) * Skv + scol;
  const unsigned short* vSrc1 = vSrc0 + (size_t)8 * Skv;

  bf16x8 qf[2][2];
  #pragma unroll
  for (int qt = 0; qt < 2; qt++){
    const unsigned short* qp = Qb + ((size_t)h * Sq + qbase + qt * 16 + r) * 64 + g * 8;
    qf[qt][0] = *(const bf16x8*)qp;
    qf[qt][1] = *(const bf16x8*)(qp + 32);
  }
  f32x4 o[2][4] = {};
  f32x4 lacc[2] = {};

  const int nkv = Skv >> 6;

  gload_lds16(kSrc0, (void*)&Ks[0][(wid * 2 + 0) * 512]);
  gload_lds16(kSrc1, (void*)&Ks[0][(wid * 2 + 1) * 512]);
  gload_lds16(vSrc0, (void*)&Vs[0][(wid * 2 + 0) * 512]);
  gload_lds16(vSrc1, (void*)&Vs[0][(wid * 2 + 1) * 512]);
  gload_lds16(kSrc0 + 4096, (void*)&Ks[1][(wid * 2 + 0) * 512]);
  gload_lds16(kSrc1 + 4096, (void*)&Ks[1][(wid * 2 + 1) * 512]);
  gload_lds16(vSrc0 + 64, (void*)&Vs[1][(wid * 2 + 0) * 512]);
  gload_lds16(vSrc1 + 64, (void*)&Vs[1][(wid * 2 + 1) * 512]);
  asm volatile("s_waitcnt vmcnt(4)" ::: "memory");
  __builtin_amdgcn_s_barrier();

  int cur = 0, stg = 2;
  for (int it = 0; it < nkv; ++it){
    if (it + 2 < nkv){
      size_t ko = (size_t)(it + 2) << 12;
      size_t vo = (size_t)(it + 2) << 6;
      gload_lds16(kSrc0 + ko, (void*)&Ks[stg][(wid * 2 + 0) * 512]);
      gload_lds16(kSrc1 + ko, (void*)&Ks[stg][(wid * 2 + 1) * 512]);
      gload_lds16(vSrc0 + vo, (void*)&Vs[stg][(wid * 2 + 0) * 512]);
      gload_lds16(vSrc1 + vo, (void*)&Vs[stg][(wid * 2 + 1) * 512]);
    }
    const short* kb = &Ks[cur][0];
    const short* vb = &Vs[cur][0];

    f32x4 pT[2][4];
    __builtin_amdgcn_s_setprio(1);
    #pragma unroll
    for (int kt = 0; kt < 4; kt++){
      int kr = kt * 16 + r;
      bf16x8 k0 = *(const bf16x8*)(kb + kr * 64 + ((g * 8) ^ ((kr & 7) << 3)));
      bf16x8 k1 = *(const bf16x8*)(kb + kr * 64 + ((32 + g * 8) ^ ((kr & 7) << 3)));
      #pragma unroll
      for (int qt = 0; qt < 2; qt++){
        f32x4 a = {};
        a = __builtin_amdgcn_mfma_f32_16x16x32_bf16(k0, qf[qt][0], a, 0, 0, 0);
        a = __builtin_amdgcn_mfma_f32_16x16x32_bf16(k1, qf[qt][1], a, 0, 0, 0);
        pT[qt][kt] = a;
      }
    }
    __builtin_amdgcn_s_setprio(0);

    #pragma unroll
    for (int qt = 0; qt < 2; qt++){
      unsigned short* pw = &Ps[wid][(qt * 16 + r) * 64];
      int rx = (r & 7) << 3;
      #pragma unroll
      for (int kt = 0; kt < 4; kt++){
        f32x4 pe;
        #pragma unroll
        for (int e = 0; e < 4; e++) pe[e] = exp2_hw(fmaf(pT[qt][kt][e], SC, -MS));
        lacc[qt] += pe;
        unsigned int w0 = cvt_pk_bf16(pe[0], pe[1]);
        unsigned int w1 = cvt_pk_bf16(pe[2], pe[3]);
        *(uint2*)(pw + ((kt * 16 + g * 4) ^ rx)) = make_uint2(w0, w1);
      }
    }

    __builtin_amdgcn_s_setprio(1);
    {
      bf16x8 pf[2][2];
      int rx = (r & 7) << 3;
      #pragma unroll
      for (int qt = 0; qt < 2; qt++){
        const unsigned short* pw = &Ps[wid][(qt * 16 + r) * 64];
        pf[qt][0] = *(const bf16x8*)(pw + ((g * 8) ^ rx));
        pf[qt][1] = *(const bf16x8*)(pw + ((32 + g * 8) ^ rx));
      }
      #pragma unroll
      for (int dj = 0; dj < 4; dj++){
        int vrow = dj * 16 + r;
        bf16x8 v0 = *(const bf16x8*)(vb + vrow * 64 + ((g * 8) ^ ((vrow & 7) << 3)));
        bf16x8 v1 = *(const bf16x8*)(vb + vrow * 64 + ((32 + g * 8) ^ ((vrow & 7) << 3)));
        #pragma unroll
        for (int qt = 0; qt < 2; qt++){
          o[qt][dj] = __builtin_amdgcn_mfma_f32_16x16x32_bf16(pf[qt][0], v0, o[qt][dj], 0, 0, 0);
          o[qt][dj] = __builtin_amdgcn_mfma_f32_16x16x32_bf16(pf[qt][1], v1, o[qt][dj], 0, 0, 0);
        }
      }
    }
    __builtin_amdgcn_s_setprio(0);

    if (it + 1 < nkv){
      if (it + 2 < nkv) asm volatile("s_waitcnt vmcnt(4)" ::: "memory");
      else              asm volatile("s_waitcnt vmcnt(0)" ::: "memory");
      __builtin_amdgcn_s_barrier();
    }
    cur = (cur == 2) ? 0 : cur + 1;
    stg = (stg == 2) ? 0 : stg + 1;
  }

  #pragma unroll
  for (int qt = 0; qt < 2; qt++){
    float s = (lacc[qt][0] + lacc[qt][1]) + (lacc[qt][2] + lacc[qt][3]);
    s += __shfl_xor(s, 16, 64);
    s += __shfl_xor(s, 32, 64);
    float inv = 1.f / s;
    int sb = lane & 48;
    #pragma unroll
    for (int j = 0; j < 4; j++){
      float aj = __shfl(inv, sb + g * 4 + j, 64);
      int qrow = qbase + qt * 16 + g * 4 + j;
      #pragma unroll
      for (int dj = 0; dj < 4; dj++)
        Out[(size_t)qrow * 1024 + h * 64 + dj * 16 + r] = f2bf(o[qt][dj][j] * aj);
    }
  }
}

extern "C" void kernel_launch(void* const* d_in, const int* in_sizes, int n_in,
                              void* d_out, int out_size, void* d_ws, size_t ws_size,
                              hipStream_t stream){
  (void)n_in; (void)out_size;
  const float* x   = (const float*)d_in[0];
  const float* emb = (const float*)d_in[1];
  const float* ctx = (const float*)d_in[2];
  int wb = 3, ri = 20;
  if (in_sizes[3] == 4096 * 64) { ri = 3; wb = 4; }
  const float* rope  = (const float*)d_in[ri];
  const float* sa_wq = (const float*)d_in[wb + 0];
  const float* sa_wk = (const float*)d_in[wb + 1];
  const float* sa_wv = (const float*)d_in[wb + 2];
  const float* sa_wo = (const float*)d_in[wb + 3];
  const float* sa_qn = (const float*)d_in[wb + 4];
  const float* sa_kn = (const float*)d_in[wb + 5];
  const float* ca_wq = (const float*)d_in[wb + 6];
  const float* ca_wk = (const float*)d_in[wb + 7];
  const float* ca_wv = (const float*)d_in[wb + 8];
  const float* ca_wo = (const float*)d_in[wb + 9];
  const float* ca_qn = (const float*)d_in[wb + 10];
  const float* ca_kn = (const float*)d_in[wb + 11];
  const float* w1    = (const float*)d_in[wb + 12];
  const float* w2    = (const float*)d_in[wb + 13];
  const float* msa   = (const float*)d_in[wb + 14];
  const float* mca   = (const float*)d_in[wb + 15];
  const float* mmlp  = (const float*)d_in[wb + 16];

  char* ws = (char*)d_ws;
  const size_t MB = 1u << 20;
  if (ws_size < 114 * MB) return;
  unsigned short* wq_sa = (unsigned short*)(ws + 0 * MB);
  unsigned short* wk_sa = (unsigned short*)(ws + 2 * MB);
  unsigned short* wv_sa = (unsigned short*)(ws + 4 * MB);
  unsigned short* wo_sa = (unsigned short*)(ws + 6 * MB);
  unsigned short* wq_ca = (unsigned short*)(ws + 8 * MB);
  unsigned short* wk_ca = (unsigned short*)(ws + 10 * MB);
  unsigned short* wv_ca = (unsigned short*)(ws + 12 * MB);
  unsigned short* wo_ca = (unsigned short*)(ws + 14 * MB);
  unsigned short* w1bf  = (unsigned short*)(ws + 16 * MB);
  unsigned short* w2bf  = (unsigned short*)(ws + 24 * MB);
  unsigned short* ctxbf = (unsigned short*)(ws + 32 * MB);
  float*          modv  = (float*)(ws + 33 * MB);
  unsigned short* hbf   = (unsigned short*)(ws + 34 * MB);
  unsigned short* qbf   = (unsigned short*)(ws + 42 * MB);
  unsigned short* kbf   = (unsigned short*)(ws + 50 * MB);
  unsigned short* aobf  = (unsigned short*)(ws + 58 * MB);
  float*          qf32  = (float*)(ws + 66 * MB);
  float*          kca32 = (float*)(ws + 82 * MB);
  unsigned short* vtb   = (unsigned short*)(ws + 98 * MB);
  unsigned short* midbf = (unsigned short*)(ws + 66 * MB);
  float*          mp0   = (float*)(ws + 34 * MB);
  float*          mp1   = (float*)(ws + 50 * MB);
  float* xcur = (float*)d_out;

  CastJobs cj;
  const float* srcs[11] = {sa_wq, sa_wk, sa_wv, sa_wo, ca_wq, ca_wk, ca_wv, ca_wo, w1, w2, ctx};
  unsigned short* dsts[11] = {wq_sa, wk_sa, wv_sa, wo_sa, wq_ca, wk_ca, wv_ca, wo_ca, w1bf, w2bf, ctxbf};
  int n4s[11] = {262144, 262144, 262144, 262144, 262144, 262144, 262144, 262144, 1048576, 1048576, 131072};
  int cum = 0;
  for (int i = 0; i < 11; i++){
    cj.src[i] = srcs[i]; cj.dst[i] = dsts[i];
    cj.blkStart[i] = cum; cum += n4s[i] / 256;
  }
  cj.blkStart[11] = cum;
  cast_all_kernel<<<cum, 256, 0, stream>>>(cj);
  modulation_kernel<<<2304, 256, 0, stream>>>(emb, msa, mca, mmlp, modv);

  // ---- self attention (QKV GEMM fuses the V transpose+cast: EPI=5, vstart=2048) ----
  ln_mod_kernel<<<4096, 256, 0, stream>>>(x, modv + 0 * 3072, hbf);
  gemm_bt_kernel<5><<<dim3(24, 32), 256, 0, stream>>>(hbf, wq_sa, 4096, 3072, 1024, qf32, vtb, nullptr, nullptr, 2048, 4096);
  qk_post2_kernel<1><<<32768, 256, 0, stream>>>(qf32, sa_qn, qf32 + 4194304, sa_kn, rope, qbf, kbf, 4096, 4096, 16384);
  attn_kernel<<<512, 256, 0, stream>>>(qbf, kbf, vtb, aobf, 4096, 4096);
  gemm_bt64_kernel<3><<<dim3(8, 64), 256, 0, stream>>>(aobf, wo_sa, 4096, 1024, 1024, xcur, nullptr, x, modv + 0 * 3072 + 2048, 0, 0);

  // ---- cross attention (ca-KV GEMM fuses V transpose: EPI=5, vstart=1024) ----
  ln_mod_kernel<<<4096, 256, 0, stream>>>(xcur, modv + 1 * 3072, hbf);
  gemm_bt64_kernel<0><<<dim3(8, 64), 256, 0, stream>>>(hbf, wq_ca, 4096, 1024, 1024, qf32, nullptr, nullptr, nullptr, 0, 0);
  gemm_bt64_kernel<5><<<dim3(16, 8), 256, 0, stream>>>(ctxbf, wk_ca, 512, 2048, 1024, kca32, vtb, nullptr, nullptr, 1024, 512);
  qk_post2_kernel<0><<<18432, 256, 0, stream>>>(qf32, ca_qn, kca32, ca_kn, nullptr, qbf, kbf, 4096, 512, 16384);
  attn_kernel<<<512, 256, 0, stream>>>(qbf, kbf, vtb, aobf, 4096, 512);
  gemm_bt64_kernel<3><<<dim3(8, 64), 256, 0, stream>>>(aobf, wo_ca, 4096, 1024, 1024, xcur, nullptr, xcur, modv + 1 * 3072 + 2048, 0, 0);

  // ---- mlp (mlp2: 128x128-tile split-K=2) ----
  ln_mod_kernel<<<4096, 256, 0, stream>>>(xcur, modv + 2 * 3072, hbf);
  gemm_bt_kernel<2><<<dim3(32, 32), 256, 0, stream>>>(hbf, w1bf, 4096, 4096, 1024, nullptr, midbf, nullptr, nullptr, 0, 0);
  gemm_bt128_sk_kernel<<<dim3(8, 32, 2), 256, 0, stream>>>(midbf, w2bf, 4096, 1024, 4096, mp0);
  reduce_gg_kernel<<<4096, 256, 0, stream>>>(mp0, mp1, modv + 2 * 3072 + 2048, xcur);
}